// Round 10
// baseline (33.000 us; speedup 1.0000x reference)
//
#include <hip/hip_runtime.h>
#include <math.h>

namespace {
constexpr int   KMAX  = 12;
constexpr int   NLINE = 313;                   // half-space (h,k) lines
constexpr int   NL25  = 25;                    // l = -12..12
constexpr int   NKV   = NLINE * NL25;          // 7825 (13 masked in stage2)
constexpr int   NKS   = 64;                    // split-K (grid.y)
constexpr int   KC    = 64;                    // particles per block
constexpr int   MROWS = 640;                   // interleaved: row 2L=Pr, 2L+1=Pi
constexpr int   NCOLS = 64;                    // interleaved: col 2ls=Rr, 2ls+1=Ri
constexpr int   S2_THREADS = NKV * 4;          // 4 lanes per k-vec
constexpr int   S2_BLOCKS  = (S2_THREADS + 255) / 256;  // 123
constexpr float ALPHA_  = 0.34f;
constexpr float TWO_PI_ = 6.283185307179586f;

typedef __attribute__((ext_vector_type(4))) _Float16 half4;
typedef __attribute__((ext_vector_type(8))) _Float16 half8;
typedef __attribute__((ext_vector_type(4))) float    f32x4;
}

__device__ __forceinline__ void cofactors(const float* __restrict__ box,
                                          float C[3][3], float* det) {
  const float b00 = box[0], b01 = box[1], b02 = box[2];
  const float b10 = box[3], b11 = box[4], b12 = box[5];
  const float b20 = box[6], b21 = box[7], b22 = box[8];
  C[0][0] =  (b11 * b22 - b12 * b21);
  C[0][1] = -(b10 * b22 - b12 * b20);
  C[0][2] =  (b10 * b21 - b11 * b20);
  C[1][0] = -(b01 * b22 - b02 * b21);
  C[1][1] =  (b00 * b22 - b02 * b20);
  C[1][2] = -(b00 * b21 - b01 * b20);
  C[2][0] =  (b01 * b12 - b02 * b11);
  C[2][1] = -(b00 * b12 - b02 * b10);
  C[2][2] =  (b00 * b11 - b01 * b10);
  *det = b00 * C[0][0] + b01 * C[0][1] + b02 * C[0][2];
}

// Half-space lines: L<300: h=1..12 x k=-12..12; L=300..311: h=0,k=1..12; L>=312: h=k=0.
__device__ __forceinline__ void line_hk(int L, int* h, int* k) {
  if (L < 300)      { *h = L / 25 + 1; *k = L % 25 - 12; }
  else if (L < 312) { *h = 0;          *k = L - 299;     }
  else              { *h = 0;          *k = 0;           }
}

// Fused: synthesize A/B fp16 phasor tiles in LDS, MFMA from LDS.
// Block = (mtg 0..9, ks 0..63): rows mtg*64..+63, particles ks*64..+63.
// Cp layout: [row 0..639][col 0..63][s 0..63] -> stage2 reads dense runs.
__global__ __launch_bounds__(256) void build_gemm(
    const float* __restrict__ coords, const float* __restrict__ box,
    const float* __restrict__ q, int N,
    float* __restrict__ Cp, float* __restrict__ out)
{
  __shared__ _Float16 Al[4][16][16][4];   // 8 KiB: 4 m-tiles x 16 kt x 16 rows x 4 k
  __shared__ _Float16 Bl[4][16][16][4];   // 8 KiB: 4 n-tiles

  const int mtg = blockIdx.x;   // 0..9
  const int ks  = blockIdx.y;   // 0..63
  if (mtg == 0 && ks == 0 && threadIdx.x == 0) out[0] = 0.0f;

  float C[3][3], det;
  cofactors(box, C, &det);
  const float invdet = 1.0f / det;

  // ---- build: 4096 Re/Im pair-entries (A: 2048, B: 2048), 16 per thread
#pragma unroll
  for (int it = 0; it < 16; ++it) {
    const int e    = threadIdx.x + it * 256;
    const int k0   = e & 3;
    const int rp   = (e >> 2) & 7;      // row-pair within tile
    const int kt   = (e >> 5) & 15;     // k-chunk of 4
    const int tile = (e >> 9) & 3;      // m-tile / n-tile
    const bool isA = e < 2048;
    const int  i   = ks * KC + kt * 4 + k0;   // particle index
    float v0 = 0.f, v1 = 0.f;
    if (i < N) {
      const float x = coords[3 * i + 0];
      const float y = coords[3 * i + 1];
      const float z = coords[3 * i + 2];
      if (isA) {
        const int L = mtg * 32 + tile * 8 + rp;   // 0..319 (>=313 junk, masked later)
        int h, k; line_hk(L, &h, &k);
        const float a = (x * C[0][0] + y * C[0][1] + z * C[0][2]) * invdet;
        const float b = (x * C[1][0] + y * C[1][1] + z * C[1][2]) * invdet;
        float t = fmaf((float)h, a, (float)k * b);       // revolutions
        float tf; asm("v_fract_f32 %0, %1" : "=v"(tf) : "v"(t));
        float s0, c0;
        asm("v_sin_f32 %0, %1" : "=v"(s0) : "v"(tf));
        asm("v_cos_f32 %0, %1" : "=v"(c0) : "v"(tf));
        const float qq = q[i];
        v0 = qq * c0; v1 = qq * s0;                      // Pr, Pi
      } else {
        const int ls = tile * 8 + rp;                    // 0..31 (>=25 junk, masked)
        const int l  = ls - KMAX;
        const float c = (x * C[2][0] + y * C[2][1] + z * C[2][2]) * invdet;
        float t = (float)l * c;
        float tf; asm("v_fract_f32 %0, %1" : "=v"(tf) : "v"(t));
        float s0, c0;
        asm("v_sin_f32 %0, %1" : "=v"(s0) : "v"(tf));
        asm("v_cos_f32 %0, %1" : "=v"(c0) : "v"(tf));
        v0 = c0; v1 = s0;                                // Rr, Ri
      }
    }
    if (isA) {
      Al[tile][kt][2 * rp + 0][k0] = (_Float16)v0;
      Al[tile][kt][2 * rp + 1][k0] = (_Float16)v1;
    } else {
      Bl[tile][kt][2 * rp + 0][k0] = (_Float16)v0;
      Bl[tile][kt][2 * rp + 1][k0] = (_Float16)v1;
    }
  }
  __syncthreads();

  // ---- MFMA: wave w owns m-tile w (16 rows x 64 cols), K = 64
  const int w    = threadIdx.x >> 6;
  const int lane = threadIdx.x & 63;
  const int r = lane & 15, g = lane >> 4;

  f32x4 acc0 = {0.f,0.f,0.f,0.f}, acc1 = {0.f,0.f,0.f,0.f};
  f32x4 acc2 = {0.f,0.f,0.f,0.f}, acc3 = {0.f,0.f,0.f,0.f};
#pragma unroll
  for (int s = 0; s < 2; ++s) {                          // 2 K-steps of 32
    union { half4 h4[2]; half8 h8; } ua;
    ua.h4[0] = *(const half4*)&Al[w][s * 8 + g][r][0];
    ua.h4[1] = *(const half4*)&Al[w][s * 8 + 4 + g][r][0];
    union { half4 h4[2]; half8 h8; } ub;
    ub.h4[0] = *(const half4*)&Bl[0][s * 8 + g][r][0];
    ub.h4[1] = *(const half4*)&Bl[0][s * 8 + 4 + g][r][0];
    acc0 = __builtin_amdgcn_mfma_f32_16x16x32_f16(ua.h8, ub.h8, acc0, 0, 0, 0);
    ub.h4[0] = *(const half4*)&Bl[1][s * 8 + g][r][0];
    ub.h4[1] = *(const half4*)&Bl[1][s * 8 + 4 + g][r][0];
    acc1 = __builtin_amdgcn_mfma_f32_16x16x32_f16(ua.h8, ub.h8, acc1, 0, 0, 0);
    ub.h4[0] = *(const half4*)&Bl[2][s * 8 + g][r][0];
    ub.h4[1] = *(const half4*)&Bl[2][s * 8 + 4 + g][r][0];
    acc2 = __builtin_amdgcn_mfma_f32_16x16x32_f16(ua.h8, ub.h8, acc2, 0, 0, 0);
    ub.h4[0] = *(const half4*)&Bl[3][s * 8 + g][r][0];
    ub.h4[1] = *(const half4*)&Bl[3][s * 8 + 4 + g][r][0];
    acc3 = __builtin_amdgcn_mfma_f32_16x16x32_f16(ua.h8, ub.h8, acc3, 0, 0, 0);
  }

  // C layout: col = lane&15, row = (lane>>4)*4 + reg  (HW-verified)
  // Cp[(R*64 + col)*64 + ks]
#pragma unroll
  for (int j = 0; j < 4; ++j) {
    const size_t R = (size_t)mtg * 64 + w * 16 + g * 4 + j;
    float* rowp = Cp + (R * NCOLS) * NKS + ks;
    rowp[(size_t)( 0 + r) * NKS] = acc0[j];
    rowp[(size_t)(16 + r) * NKS] = acc1[j];
    rowp[(size_t)(32 + r) * NKS] = acc2[j];
    rowp[(size_t)(48 + r) * NKS] = acc3[j];
  }
}

// 4 lanes per k-vec: each sums 16 splits (dense float4 runs), shfl-combine,
// weight by fac, block-reduce, one atomicAdd per block.
__global__ __launch_bounds__(256) void stage2(
    const float* __restrict__ Cp, const float* __restrict__ box,
    float* __restrict__ out)
{
  __shared__ float red[256];
  const int tid = blockIdx.x * 256 + threadIdx.x;
  const int kv  = tid >> 2;
  const int sq  = tid & 3;          // s-quarter: 16 splits each
  float Sre = 0.f, Sim = 0.f;
  bool valid = false;
  int h = 0, k = 0, l = 0;
  if (kv < NKV) {
    const int L  = kv / NL25;
    const int ls = kv % NL25;
    l = ls - KMAX;
    line_hk(L, &h, &k);
    valid = !(h == 0 && k == 0 && l <= 0);
    if (valid) {
      const float* prr = Cp + ((size_t)(2 * L + 0) * NCOLS + 2 * ls + 0) * NKS + sq * 16;
      const float* pri = Cp + ((size_t)(2 * L + 0) * NCOLS + 2 * ls + 1) * NKS + sq * 16;
      const float* pir = Cp + ((size_t)(2 * L + 1) * NCOLS + 2 * ls + 0) * NKS + sq * 16;
      const float* pii = Cp + ((size_t)(2 * L + 1) * NCOLS + 2 * ls + 1) * NKS + sq * 16;
#pragma unroll
      for (int v = 0; v < 4; ++v) {
        const float4 a = ((const float4*)prr)[v];
        const float4 b = ((const float4*)pri)[v];
        const float4 c = ((const float4*)pir)[v];
        const float4 d = ((const float4*)pii)[v];
        Sre += (a.x - d.x) + (a.y - d.y) + (a.z - d.z) + (a.w - d.w);
        Sim += (b.x + c.x) + (b.y + c.y) + (b.z + c.z) + (b.w + c.w);
      }
    }
  }
  // combine the 4 s-quarters (lanes 4t..4t+3)
  Sre += __shfl_xor(Sre, 1); Sre += __shfl_xor(Sre, 2);
  Sim += __shfl_xor(Sim, 1); Sim += __shfl_xor(Sim, 2);

  float e = 0.f;
  if (kv < NKV && valid && sq == 0) {
    float C[3][3], det;
    cofactors(box, C, &det);
    const float invdet = 1.0f / det;
    const float hf = (float)h, kf = (float)k, lf = (float)l;
    const float kx = (hf * C[0][0] + kf * C[1][0] + lf * C[2][0]) * invdet;
    const float ky = (hf * C[0][1] + kf * C[1][1] + lf * C[2][1]) * invdet;
    const float kz = (hf * C[0][2] + kf * C[1][2] + lf * C[2][2]) * invdet;
    const float k2 = TWO_PI_ * TWO_PI_ * (kx * kx + ky * ky + kz * kz);
    const float fac = __expf(-k2 / (4.0f * ALPHA_ * ALPHA_)) / k2;
    e = fac * fmaf(Sre, Sre, Sim * Sim);
  }
  red[threadIdx.x] = e;
  __syncthreads();
  for (int s = 128; s > 0; s >>= 1) {
    if (threadIdx.x < s) red[threadIdx.x] += red[threadIdx.x + s];
    __syncthreads();
  }
  if (threadIdx.x == 0) {
    float C[3][3], det;
    cofactors(box, C, &det);
    // E = (2*pi/V)*full_sum = (4*pi/V)*half_sum
    const float scale = (4.0f * 3.14159265358979323846f) / fabsf(det);
    atomicAdd(out, scale * red[0]);
  }
}

extern "C" void kernel_launch(void* const* d_in, const int* in_sizes, int n_in,
                              void* d_out, int out_size, void* d_ws, size_t ws_size,
                              hipStream_t stream) {
  const float* coords = (const float*)d_in[0];
  const float* box    = (const float*)d_in[1];
  const float* q      = (const float*)d_in[2];
  float* out = (float*)d_out;
  const int N = in_sizes[2];

  // ws: Cp = 640*64*64 f32 = 10,485,760 B
  float* Cp = (float*)d_ws;

  hipLaunchKernelGGL(build_gemm, dim3(10, NKS), dim3(256), 0, stream,
                     coords, box, q, N, Cp, out);
  hipLaunchKernelGGL(stage2, dim3(S2_BLOCKS), dim3(256), 0, stream,
                     Cp, box, out);
}

// Round 11
// 23.036 us; speedup vs baseline: 1.4326x; 1.4326x over previous
//
#include <hip/hip_runtime.h>
#include <math.h>

namespace {
constexpr int   KMAX   = 12;
constexpr int   NLINE  = 313;                   // half-space (h,k) lines
constexpr int   NL25   = 25;
constexpr int   NKV    = NLINE * NL25;          // 7825 (13 masked in stage2)
constexpr int   NG     = NLINE * 5;             // 1565 l-groups of 5
constexpr int   GPAD   = 7 * 256;               // 1792 padded groups
constexpr int   NSLICE = 128;                   // particle slices
constexpr int   PART   = 32;                    // particles per slice (128*32=4096)
constexpr int   S2_BLOCKS = (NKV * 4 + 255) / 256;  // 123
constexpr float ALPHA_  = 0.34f;
constexpr float TWO_PI_ = 6.283185307179586f;
}

__device__ __forceinline__ void cofactors(const float* __restrict__ box,
                                          float C[3][3], float* det) {
  const float b00 = box[0], b01 = box[1], b02 = box[2];
  const float b10 = box[3], b11 = box[4], b12 = box[5];
  const float b20 = box[6], b21 = box[7], b22 = box[8];
  C[0][0] =  (b11 * b22 - b12 * b21);
  C[0][1] = -(b10 * b22 - b12 * b20);
  C[0][2] =  (b10 * b21 - b11 * b20);
  C[1][0] = -(b01 * b22 - b02 * b21);
  C[1][1] =  (b00 * b22 - b02 * b20);
  C[1][2] = -(b00 * b21 - b01 * b20);
  C[2][0] =  (b01 * b12 - b02 * b11);
  C[2][1] = -(b00 * b12 - b02 * b10);
  C[2][2] =  (b00 * b11 - b01 * b10);
  *det = b00 * C[0][0] + b01 * C[0][1] + b02 * C[0][2];
}

// Half-space lines: L<300: h=1..12 x k=-12..12; L=300..311: h=0,k=1..12; L=312: h=k=0.
__device__ __forceinline__ void line_hk(int L, int* h, int* k) {
  if (L < 300)      { *h = L / 25 + 1; *k = L % 25 - 12; }
  else if (L < 312) { *h = 0;          *k = L - 299;     }
  else              { *h = 0;          *k = 0;           }
}

// Transposed: lane = one l-group of 5; loop = particles (LDS broadcast).
// No cross-lane reduction. Block = (kblk 0..6, slice 0..127); 32 particles/slice.
__global__ __launch_bounds__(256, 8) void ewald_t(
    const float* __restrict__ coords, const float* __restrict__ box,
    const float* __restrict__ q, int N, float2* __restrict__ partial,
    float* __restrict__ out)
{
  __shared__ float4 sf4[PART];   // (a, b, cr, sr)
  __shared__ float2 sf2[PART];   // (c, q)

  const int slice = blockIdx.y;
  if (blockIdx.x == 0 && slice == 0 && threadIdx.x == 0) out[0] = 0.0f;

  // ---- stage this slice's 32 particles (threads 0..31)
  if (threadIdx.x < PART) {
    float C[3][3], det;
    cofactors(box, C, &det);
    const float invdet = 1.0f / det;
    const int i = slice * PART + threadIdx.x;
    float4 v4 = make_float4(0.f, 0.f, 1.f, 0.f);
    float2 v2 = make_float2(0.f, 0.f);
    if (i < N) {
      const float x = coords[3 * i + 0];
      const float y = coords[3 * i + 1];
      const float z = coords[3 * i + 2];
      v4.x = (x * C[0][0] + y * C[0][1] + z * C[0][2]) * invdet;   // a
      v4.y = (x * C[1][0] + y * C[1][1] + z * C[1][2]) * invdet;   // b
      float c = (x * C[2][0] + y * C[2][1] + z * C[2][2]) * invdet;
      c = c - floorf(c);                                           // c in [0,1)
      float cr, sr;
      asm("v_sin_f32 %0, %1" : "=v"(sr) : "v"(c));                 // e^{2*pi*i*c}
      asm("v_cos_f32 %0, %1" : "=v"(cr) : "v"(c));
      v4.z = cr; v4.w = sr;
      v2.x = c;  v2.y = q[i];
    }
    sf4[threadIdx.x] = v4;
    sf2[threadIdx.x] = v2;
  }
  __syncthreads();

  // ---- each thread owns group gg: line L = gg/5, l0 = -12 + 5*(gg%5)
  const int gg  = blockIdx.x * 256 + threadIdx.x;
  const int ggc = (gg < NG) ? gg : (NG - 1);
  int h, k; line_hk(ggc / 5, &h, &k);
  const float hf  = (float)h;
  const float kf  = (float)k;
  const float l0f = (float)(-KMAX + 5 * (ggc % 5));

  float Sre[5] = {0.f, 0.f, 0.f, 0.f, 0.f};
  float Sim[5] = {0.f, 0.f, 0.f, 0.f, 0.f};

#pragma unroll 4
  for (int j = 0; j < PART; ++j) {
    const float4 p = sf4[j];   // block-uniform address -> LDS broadcast
    const float2 w = sf2[j];
    float t0 = fmaf(hf, p.x, fmaf(kf, p.y, l0f * w.x));  // phase(l0), revolutions
    float tf;
    asm("v_fract_f32 %0, %1" : "=v"(tf) : "v"(t0));
    float s0, c0;
    asm("v_sin_f32 %0, %1" : "=v"(s0) : "v"(tf));
    asm("v_cos_f32 %0, %1" : "=v"(c0) : "v"(tf));
    float Pre = w.y * c0, Pim = w.y * s0;                // q folded into phasor
    Sre[0] += Pre; Sim[0] += Pim;
    const float cr = p.z, sr = p.w;
#pragma unroll
    for (int u = 1; u < 5; ++u) {
      const float nre = fmaf(Pre, cr, -(Pim * sr));
      const float nim = fmaf(Pre, sr,  (Pim * cr));
      Pre = nre; Pim = nim;
      Sre[u] += Pre; Sim[u] += Pim;
    }
  }

  // ---- store: [slice][group][u] -> each lane writes 40B contiguous (coalesced)
  if (gg < NG) {
    float2* dst = partial + ((size_t)slice * GPAD + gg) * 5;
#pragma unroll
    for (int u = 0; u < 5; ++u) dst[u] = make_float2(Sre[u], Sim[u]);
  }
}

// 4 lanes per kvec, 32 slice-summands each (coalesced across the wave per slice),
// shfl-combine, weight by fac, block-reduce, one atomicAdd per block.
__global__ __launch_bounds__(256) void stage2(
    const float2* __restrict__ partial, const float* __restrict__ box,
    float* __restrict__ out)
{
  __shared__ float red[256];
  const int tid = blockIdx.x * 256 + threadIdx.x;
  const int kv  = tid >> 2;
  const int sq  = tid & 3;
  float Sre = 0.f, Sim = 0.f;
  bool valid = false;
  int h = 0, k = 0, l = 0;
  if (kv < NKV) {
    const int L  = kv / NL25;
    const int ls = kv % NL25;
    l = ls - KMAX;
    line_hk(L, &h, &k);
    valid = !(h == 0 && k == 0 && l <= 0);   // mask non-half-space entries
    if (valid) {
      const int g = L * 5 + ls / 5;
      const int u = ls % 5;
      for (int s = sq * 32; s < sq * 32 + 32; ++s) {
        const float2 p = partial[((size_t)s * GPAD + g) * 5 + u];
        Sre += p.x; Sim += p.y;
      }
    }
  }
  Sre += __shfl_xor(Sre, 1); Sre += __shfl_xor(Sre, 2);
  Sim += __shfl_xor(Sim, 1); Sim += __shfl_xor(Sim, 2);

  float e = 0.f;
  if (kv < NKV && valid && sq == 0) {
    float C[3][3], det;
    cofactors(box, C, &det);
    const float invdet = 1.0f / det;
    const float hf = (float)h, kf = (float)k, lf = (float)l;
    const float kx = (hf * C[0][0] + kf * C[1][0] + lf * C[2][0]) * invdet;
    const float ky = (hf * C[0][1] + kf * C[1][1] + lf * C[2][1]) * invdet;
    const float kz = (hf * C[0][2] + kf * C[1][2] + lf * C[2][2]) * invdet;
    const float k2 = TWO_PI_ * TWO_PI_ * (kx * kx + ky * ky + kz * kz);
    const float fac = __expf(-k2 / (4.0f * ALPHA_ * ALPHA_)) / k2;
    e = fac * fmaf(Sre, Sre, Sim * Sim);
  }
  red[threadIdx.x] = e;
  __syncthreads();
  for (int s = 128; s > 0; s >>= 1) {
    if (threadIdx.x < s) red[threadIdx.x] += red[threadIdx.x + s];
    __syncthreads();
  }
  if (threadIdx.x == 0) {
    float C[3][3], det;
    cofactors(box, C, &det);
    // E = (2*pi/V)*full_sum = (4*pi/V)*half_sum
    const float scale = (4.0f * 3.14159265358979323846f) / fabsf(det);
    atomicAdd(out, scale * red[0]);
  }
}

extern "C" void kernel_launch(void* const* d_in, const int* in_sizes, int n_in,
                              void* d_out, int out_size, void* d_ws, size_t ws_size,
                              hipStream_t stream) {
  const float* coords = (const float*)d_in[0];
  const float* box    = (const float*)d_in[1];
  const float* q      = (const float*)d_in[2];
  float* out = (float*)d_out;
  const int N = in_sizes[2];

  // ws: partial = NSLICE * GPAD * 5 float2 = 9,175,040 B
  float2* partial = (float2*)d_ws;

  hipLaunchKernelGGL(ewald_t, dim3(7, NSLICE), dim3(256), 0, stream,
                     coords, box, q, N, partial, out);
  hipLaunchKernelGGL(stage2, dim3(S2_BLOCKS), dim3(256), 0, stream,
                     partial, box, out);
}

// Round 12
// 21.554 us; speedup vs baseline: 1.5310x; 1.0687x over previous
//
#include <hip/hip_runtime.h>
#include <math.h>

namespace {
constexpr int   KMAX   = 12;
constexpr int   NLINE  = 313;                   // half-space (h,k) lines
constexpr int   NL25   = 25;
constexpr int   NKV    = NLINE * NL25;          // 7825 (13 masked in stage2)
constexpr int   NG     = NLINE * 5;             // 1565 l-groups of 5
constexpr int   GPAD   = 7 * 256;               // 1792 padded groups
constexpr int   KROW   = GPAD * 5;              // 8960 floats2 per slice row
constexpr int   NSLICE = 128;                   // particle slices
constexpr int   PART   = 32;                    // particles per slice (128*32=4096)
constexpr int   S2_BLOCKS = (NKV + 63) / 64;    // 123 (64 kvecs per block)
constexpr float ALPHA_  = 0.34f;
constexpr float TWO_PI_ = 6.283185307179586f;
}

__device__ __forceinline__ void cofactors(const float* __restrict__ box,
                                          float C[3][3], float* det) {
  const float b00 = box[0], b01 = box[1], b02 = box[2];
  const float b10 = box[3], b11 = box[4], b12 = box[5];
  const float b20 = box[6], b21 = box[7], b22 = box[8];
  C[0][0] =  (b11 * b22 - b12 * b21);
  C[0][1] = -(b10 * b22 - b12 * b20);
  C[0][2] =  (b10 * b21 - b11 * b20);
  C[1][0] = -(b01 * b22 - b02 * b21);
  C[1][1] =  (b00 * b22 - b02 * b20);
  C[1][2] = -(b00 * b21 - b01 * b20);
  C[2][0] =  (b01 * b12 - b02 * b11);
  C[2][1] = -(b00 * b12 - b02 * b10);
  C[2][2] =  (b00 * b11 - b01 * b10);
  *det = b00 * C[0][0] + b01 * C[0][1] + b02 * C[0][2];
}

// Half-space lines: L<300: h=1..12 x k=-12..12; L=300..311: h=0,k=1..12; L=312: h=k=0.
__device__ __forceinline__ void line_hk(int L, int* h, int* k) {
  if (L < 300)      { *h = L / 25 + 1; *k = L % 25 - 12; }
  else if (L < 312) { *h = 0;          *k = L - 299;     }
  else              { *h = 0;          *k = 0;           }
}

// Transposed: lane = one l-group of 5; loop = particles (LDS broadcast).
// No cross-lane reduction. Block = (kblk 0..6, slice 0..127); 32 particles/slice.
// NOTE: no forced min-occupancy (R11's launch_bounds(256,8) risked spills).
__global__ __launch_bounds__(256) void ewald_t(
    const float* __restrict__ coords, const float* __restrict__ box,
    const float* __restrict__ q, int N, float2* __restrict__ partial,
    float* __restrict__ out)
{
  __shared__ float4 sf4[PART];   // (a, b, cr, sr)
  __shared__ float2 sf2[PART];   // (c, q)

  const int slice = blockIdx.y;
  if (blockIdx.x == 0 && slice == 0 && threadIdx.x == 0) out[0] = 0.0f;

  // ---- stage this slice's 32 particles (threads 0..31)
  if (threadIdx.x < PART) {
    float C[3][3], det;
    cofactors(box, C, &det);
    const float invdet = 1.0f / det;
    const int i = slice * PART + threadIdx.x;
    float4 v4 = make_float4(0.f, 0.f, 1.f, 0.f);
    float2 v2 = make_float2(0.f, 0.f);
    if (i < N) {
      const float x = coords[3 * i + 0];
      const float y = coords[3 * i + 1];
      const float z = coords[3 * i + 2];
      v4.x = (x * C[0][0] + y * C[0][1] + z * C[0][2]) * invdet;   // a
      v4.y = (x * C[1][0] + y * C[1][1] + z * C[1][2]) * invdet;   // b
      float c = (x * C[2][0] + y * C[2][1] + z * C[2][2]) * invdet;
      c = c - floorf(c);                                           // c in [0,1)
      float cr, sr;
      asm("v_sin_f32 %0, %1" : "=v"(sr) : "v"(c));                 // e^{2*pi*i*c}
      asm("v_cos_f32 %0, %1" : "=v"(cr) : "v"(c));
      v4.z = cr; v4.w = sr;
      v2.x = c;  v2.y = q[i];
    }
    sf4[threadIdx.x] = v4;
    sf2[threadIdx.x] = v2;
  }
  __syncthreads();

  // ---- each thread owns group gg: line L = gg/5, l0 = -12 + 5*(gg%5)
  const int gg  = blockIdx.x * 256 + threadIdx.x;
  const int ggc = (gg < NG) ? gg : (NG - 1);
  int h, k; line_hk(ggc / 5, &h, &k);
  const float hf  = (float)h;
  const float kf  = (float)k;
  const float l0f = (float)(-KMAX + 5 * (ggc % 5));

  float Sre[5] = {0.f, 0.f, 0.f, 0.f, 0.f};
  float Sim[5] = {0.f, 0.f, 0.f, 0.f, 0.f};

#pragma unroll 2
  for (int j = 0; j < PART; ++j) {
    const float4 p = sf4[j];   // block-uniform address -> LDS broadcast
    const float2 w = sf2[j];
    float t0 = fmaf(hf, p.x, fmaf(kf, p.y, l0f * w.x));  // phase(l0), revolutions
    float tf;
    asm("v_fract_f32 %0, %1" : "=v"(tf) : "v"(t0));
    float s0, c0;
    asm("v_sin_f32 %0, %1" : "=v"(s0) : "v"(tf));
    asm("v_cos_f32 %0, %1" : "=v"(c0) : "v"(tf));
    float Pre = w.y * c0, Pim = w.y * s0;                // q folded into phasor
    Sre[0] += Pre; Sim[0] += Pim;
    const float cr = p.z, sr = p.w;
#pragma unroll
    for (int u = 1; u < 5; ++u) {
      const float nre = fmaf(Pre, cr, -(Pim * sr));
      const float nim = fmaf(Pre, sr,  (Pim * cr));
      Pre = nre; Pim = nim;
      Sre[u] += Pre; Sim[u] += Pim;
    }
  }

  // ---- store: [slice][kvidx] (kvidx = gg*5+u = L*25+ls); 40B/lane contiguous
  if (gg < NG) {
    float2* dst = partial + (size_t)slice * KROW + gg * 5;
#pragma unroll
    for (int u = 0; u < 5; ++u) dst[u] = make_float2(Sre[u], Sim[u]);
  }
}

// Coalesced stage2: wave = 16 kvecs x 4 s-quarters (sq = lane>>4, kvl = lane&15).
// 16 adjacent lanes read contiguous 128B runs; combine via shfl_xor 16/32.
__global__ __launch_bounds__(256) void stage2(
    const float2* __restrict__ partial, const float* __restrict__ box,
    float* __restrict__ out)
{
  __shared__ float red[256];
  const int lane = threadIdx.x & 63;
  const int sq   = lane >> 4;         // s-quarter: 32 slices each
  const int kvl  = lane & 15;
  const int kv   = blockIdx.x * 64 + (threadIdx.x >> 6) * 16 + kvl;

  float Sre = 0.f, Sim = 0.f;
  bool valid = false;
  int h = 0, k = 0, l = 0;
  if (kv < NKV) {
    const int L  = kv / NL25;
    const int ls = kv % NL25;
    l = ls - KMAX;
    line_hk(L, &h, &k);
    valid = !(h == 0 && k == 0 && l <= 0);   // mask non-half-space entries
    for (int s = sq * 32; s < sq * 32 + 32; ++s) {
      const float2 p = partial[(size_t)s * KROW + kv];
      Sre += p.x; Sim += p.y;
    }
  }
  Sre += __shfl_xor(Sre, 16); Sre += __shfl_xor(Sre, 32);
  Sim += __shfl_xor(Sim, 16); Sim += __shfl_xor(Sim, 32);

  float e = 0.f;
  if (kv < NKV && valid && sq == 0) {
    float C[3][3], det;
    cofactors(box, C, &det);
    const float invdet = 1.0f / det;
    const float hf = (float)h, kf = (float)k, lf = (float)l;
    const float kx = (hf * C[0][0] + kf * C[1][0] + lf * C[2][0]) * invdet;
    const float ky = (hf * C[0][1] + kf * C[1][1] + lf * C[2][1]) * invdet;
    const float kz = (hf * C[0][2] + kf * C[1][2] + lf * C[2][2]) * invdet;
    const float k2 = TWO_PI_ * TWO_PI_ * (kx * kx + ky * ky + kz * kz);
    const float fac = __expf(-k2 / (4.0f * ALPHA_ * ALPHA_)) / k2;
    e = fac * fmaf(Sre, Sre, Sim * Sim);
  }
  red[threadIdx.x] = e;
  __syncthreads();
  for (int s = 128; s > 0; s >>= 1) {
    if (threadIdx.x < s) red[threadIdx.x] += red[threadIdx.x + s];
    __syncthreads();
  }
  if (threadIdx.x == 0) {
    float C[3][3], det;
    cofactors(box, C, &det);
    // E = (2*pi/V)*full_sum = (4*pi/V)*half_sum
    const float scale = (4.0f * 3.14159265358979323846f) / fabsf(det);
    atomicAdd(out, scale * red[0]);
  }
}

extern "C" void kernel_launch(void* const* d_in, const int* in_sizes, int n_in,
                              void* d_out, int out_size, void* d_ws, size_t ws_size,
                              hipStream_t stream) {
  const float* coords = (const float*)d_in[0];
  const float* box    = (const float*)d_in[1];
  const float* q      = (const float*)d_in[2];
  float* out = (float*)d_out;
  const int N = in_sizes[2];

  // ws: partial = NSLICE * KROW float2 = 9,175,040 B
  float2* partial = (float2*)d_ws;

  hipLaunchKernelGGL(ewald_t, dim3(7, NSLICE), dim3(256), 0, stream,
                     coords, box, q, N, partial, out);
  hipLaunchKernelGGL(stage2, dim3(S2_BLOCKS), dim3(256), 0, stream,
                     partial, box, out);
}